// Round 3
// baseline (91.328 us; speedup 1.0000x reference)
//
#include <hip/hip_runtime.h>
#include <math.h>

#define N_RAYS   262144
#define HIDDEN   256
#define NEAR_T   1.0f
#define FAR_T    10.0f
#define MAX_IT   64

#define RPT    2
#define BLOCK  256
#define HALF   (N_RAYS / 2)      // 131072

// Fused sphere-trace + MLP, 2 rays/thread.
// Weights packed per-j into two float4 LDS records -> 2 broadcast ds_read_b128
// per j (compile-time offsets), 14 FMAs per j. Trace in scalar form:
// f(t) = sqrt((t+B)^2 + C) - rad with C the cancellation-free perp-dist^2.
__global__ __launch_bounds__(BLOCK)
void st_fused2(const float* __restrict__ org,
               const float* __restrict__ dir,
               const float* __restrict__ center,
               const float* __restrict__ radius,
               const float* __restrict__ w1,
               const float* __restrict__ b1,
               const float* __restrict__ w2,
               const float* __restrict__ b2,
               float* __restrict__ out) {
    __shared__ float4 s_rec[2 * HIDDEN];   // 8 KB

    for (int j = threadIdx.x; j < HIDDEN; j += BLOCK) {
        s_rec[2*j+0] = make_float4(w1[j], w1[HIDDEN + j], w1[2*HIDDEN + j], b1[j]);
        s_rec[2*j+1] = make_float4(w2[3*j+0], w2[3*j+1], w2[3*j+2], 0.0f);
    }
    __syncthreads();

    const int rA = blockIdx.x * BLOCK + threadIdx.x;
    const int rB = rA + HALF;

    const float cx = center[0], cy = center[1], cz = center[2];
    const float rad = radius[0];

    const float oxA = org[3*rA+0], oyA = org[3*rA+1], ozA = org[3*rA+2];
    const float dxA = dir[3*rA+0], dyA = dir[3*rA+1], dzA = dir[3*rA+2];
    const float oxB = org[3*rB+0], oyB = org[3*rB+1], ozB = org[3*rB+2];
    const float dxB = dir[3*rB+0], dyB = dir[3*rB+1], dzB = dir[3*rB+2];

    // q = o - c;  B = q.d;  C = |q - B d|^2
    const float qxA = oxA - cx, qyA = oyA - cy, qzA = ozA - cz;
    const float BA  = qxA*dxA + qyA*dyA + qzA*dzA;
    const float exA = __builtin_fmaf(-BA, dxA, qxA);
    const float eyA = __builtin_fmaf(-BA, dyA, qyA);
    const float ezA = __builtin_fmaf(-BA, dzA, qzA);
    const float CA  = exA*exA + eyA*eyA + ezA*ezA;

    const float qxB = oxB - cx, qyB = oyB - cy, qzB = ozB - cz;
    const float BB  = qxB*dxB + qyB*dyB + qzB*dzB;
    const float exB = __builtin_fmaf(-BB, dxB, qxB);
    const float eyB = __builtin_fmaf(-BB, dyB, qyB);
    const float ezB = __builtin_fmaf(-BB, dzB, qzB);
    const float CB  = exB*exB + eyB*eyB + ezB*ezB;

    float uA = NEAR_T + BA;
    float uB = NEAR_T + BB;
    #pragma unroll
    for (int i = 0; i < MAX_IT; ++i) {
        const float fA = __builtin_amdgcn_sqrtf(__builtin_fmaf(uA, uA, CA)) - rad;
        const float fB = __builtin_amdgcn_sqrtf(__builtin_fmaf(uB, uB, CB)) - rad;
        uA += fA;
        uB += fB;
    }
    const float tA = uA - BA, tB = uB - BB;
    const bool hitA = (tA <= FAR_T), hitB = (tB <= FAR_T);

    const float pxA = __builtin_fmaf(tA, dxA, oxA);
    const float pyA = __builtin_fmaf(tA, dyA, oyA);
    const float pzA = __builtin_fmaf(tA, dzA, ozA);
    const float pxB = __builtin_fmaf(tB, dxB, oxB);
    const float pyB = __builtin_fmaf(tB, dyB, oyB);
    const float pzB = __builtin_fmaf(tB, dzB, ozB);

    const float bb0 = b2[0], bb1 = b2[1], bb2 = b2[2];
    float a0A = bb0, a1A = bb1, a2A = bb2;
    float a0B = bb0, a1B = bb1, a2B = bb2;

    const float4* __restrict__ rec = s_rec;
    #pragma unroll 16
    for (int j = 0; j < HIDDEN; ++j) {
        const float4 lo = rec[2*j+0];
        const float4 hi = rec[2*j+1];
        float hA = __builtin_fmaf(pxA, lo.x,
                   __builtin_fmaf(pyA, lo.y,
                   __builtin_fmaf(pzA, lo.z, lo.w)));
        float hB = __builtin_fmaf(pxB, lo.x,
                   __builtin_fmaf(pyB, lo.y,
                   __builtin_fmaf(pzB, lo.z, lo.w)));
        hA = fmaxf(hA, 0.0f);
        hB = fmaxf(hB, 0.0f);
        a0A = __builtin_fmaf(hA, hi.x, a0A);
        a1A = __builtin_fmaf(hA, hi.y, a1A);
        a2A = __builtin_fmaf(hA, hi.z, a2A);
        a0B = __builtin_fmaf(hB, hi.x, a0B);
        a1B = __builtin_fmaf(hB, hi.y, a1B);
        a2B = __builtin_fmaf(hB, hi.z, a2B);
    }

    const float s0A = 1.0f / (1.0f + __expf(-a0A));
    const float s1A = 1.0f / (1.0f + __expf(-a1A));
    const float s2A = 1.0f / (1.0f + __expf(-a2A));
    const float s0B = 1.0f / (1.0f + __expf(-a0B));
    const float s1B = 1.0f / (1.0f + __expf(-a1B));
    const float s2B = 1.0f / (1.0f + __expf(-a2B));

    out[3*rA+0] = hitA ? s0A : 0.0f;
    out[3*rA+1] = hitA ? s1A : 0.0f;
    out[3*rA+2] = hitA ? s2A : 0.0f;
    out[3*rB+0] = hitB ? s0B : 0.0f;
    out[3*rB+1] = hitB ? s1B : 0.0f;
    out[3*rB+2] = hitB ? s2B : 0.0f;
}

extern "C" void kernel_launch(void* const* d_in, const int* in_sizes, int n_in,
                              void* d_out, int out_size, void* d_ws, size_t ws_size,
                              hipStream_t stream) {
    const float* org    = (const float*)d_in[0];
    const float* dir    = (const float*)d_in[1];
    const float* center = (const float*)d_in[2];
    const float* radius = (const float*)d_in[3];
    const float* w1     = (const float*)d_in[4];
    const float* b1     = (const float*)d_in[5];
    const float* w2     = (const float*)d_in[6];
    const float* b2     = (const float*)d_in[7];
    float* out = (float*)d_out;

    const int grid = HALF / BLOCK;   // 512
    st_fused2<<<grid, BLOCK, 0, stream>>>(org, dir, center, radius,
                                          w1, b1, w2, b2, out);
}

// Round 4
// 88.858 us; speedup vs baseline: 1.0278x; 1.0278x over previous
//
#include <hip/hip_runtime.h>
#include <math.h>

#define N_RAYS   262144
#define HIDDEN   256
#define NEAR_T   1.0f
#define FAR_T    10.0f
#define MAX_IT   64

#define RPT     4
#define BLOCK   256
#define STRIDE  (N_RAYS / RPT)    // 65536
#define JQ      (HIDDEN / 4)      // 64 float4 groups

// Fused sphere-trace + MLP, 4 rays/thread.
// Weights in 7 structure-of-float4 LDS arrays -> 7 broadcast ds_read_b128 per
// 4 hidden units, shared across 4 rays (448 LDS reads/wave total).
// Trace in scalar form: f(t) = sqrt((t+B)^2 + C) - rad, 4 chains interleaved.
__global__ __launch_bounds__(BLOCK)
void st_fused4(const float* __restrict__ org,
               const float* __restrict__ dir,
               const float* __restrict__ center,
               const float* __restrict__ radius,
               const float* __restrict__ w1,
               const float* __restrict__ b1,
               const float* __restrict__ w2,
               const float* __restrict__ b2,
               float* __restrict__ out) {
    __shared__ float4 s_wx[JQ], s_wy[JQ], s_wz[JQ], s_wb[JQ];
    __shared__ float4 s_wa[JQ], s_wv[JQ], s_wc[JQ];

    {   // one j per thread (BLOCK == HIDDEN)
        const int j = threadIdx.x;
        ((float*)s_wx)[j] = w1[0*HIDDEN + j];
        ((float*)s_wy)[j] = w1[1*HIDDEN + j];
        ((float*)s_wz)[j] = w1[2*HIDDEN + j];
        ((float*)s_wb)[j] = b1[j];
        ((float*)s_wa)[j] = w2[3*j+0];
        ((float*)s_wv)[j] = w2[3*j+1];
        ((float*)s_wc)[j] = w2[3*j+2];
    }
    __syncthreads();

    const int r0 = blockIdx.x * BLOCK + threadIdx.x;

    const float cx = center[0], cy = center[1], cz = center[2];
    const float rad = radius[0];

    float px[RPT], py[RPT], pz[RPT];
    bool  hit[RPT];

    // ---- trace: 4 interleaved scalar-form chains ----
    {
        float Bq[RPT], Cq[RPT], u[RPT];
        float dxs[RPT], dys[RPT], dzs[RPT], oxs[RPT], oys[RPT], ozs[RPT];
        #pragma unroll
        for (int k = 0; k < RPT; ++k) {
            const int r = r0 + k * STRIDE;
            const float ox = org[3*r+0], oy = org[3*r+1], oz = org[3*r+2];
            const float dx = dir[3*r+0], dy = dir[3*r+1], dz = dir[3*r+2];
            oxs[k]=ox; oys[k]=oy; ozs[k]=oz; dxs[k]=dx; dys[k]=dy; dzs[k]=dz;
            const float qx = ox - cx, qy = oy - cy, qz = oz - cz;
            const float B  = qx*dx + qy*dy + qz*dz;
            const float ex = __builtin_fmaf(-B, dx, qx);
            const float ey = __builtin_fmaf(-B, dy, qy);
            const float ez = __builtin_fmaf(-B, dz, qz);
            Bq[k] = B;
            Cq[k] = ex*ex + ey*ey + ez*ez;
            u[k]  = NEAR_T + B;
        }
        #pragma unroll
        for (int i = 0; i < MAX_IT; ++i) {
            #pragma unroll
            for (int k = 0; k < RPT; ++k) {
                const float f = __builtin_amdgcn_sqrtf(
                                    __builtin_fmaf(u[k], u[k], Cq[k])) - rad;
                u[k] += f;
            }
        }
        #pragma unroll
        for (int k = 0; k < RPT; ++k) {
            const float t = u[k] - Bq[k];
            hit[k] = (t <= FAR_T);
            px[k] = __builtin_fmaf(t, dxs[k], oxs[k]);
            py[k] = __builtin_fmaf(t, dys[k], oys[k]);
            pz[k] = __builtin_fmaf(t, dzs[k], ozs[k]);
        }
    }

    // ---- MLP ----
    const float bb0 = b2[0], bb1 = b2[1], bb2 = b2[2];
    float a0[RPT], a1[RPT], a2[RPT];
    #pragma unroll
    for (int k = 0; k < RPT; ++k) { a0[k]=bb0; a1[k]=bb1; a2[k]=bb2; }

    #pragma unroll 2
    for (int jq = 0; jq < JQ; ++jq) {
        const float4 wx = s_wx[jq], wy = s_wy[jq], wz = s_wz[jq], wb = s_wb[jq];
        const float4 wa = s_wa[jq], wv = s_wv[jq], wc = s_wc[jq];
        #pragma unroll
        for (int k = 0; k < RPT; ++k) {
            float h;
            h = __builtin_fmaf(px[k], wx.x, __builtin_fmaf(py[k], wy.x,
                __builtin_fmaf(pz[k], wz.x, wb.x)));
            h = fmaxf(h, 0.0f);
            a0[k] = __builtin_fmaf(h, wa.x, a0[k]);
            a1[k] = __builtin_fmaf(h, wv.x, a1[k]);
            a2[k] = __builtin_fmaf(h, wc.x, a2[k]);

            h = __builtin_fmaf(px[k], wx.y, __builtin_fmaf(py[k], wy.y,
                __builtin_fmaf(pz[k], wz.y, wb.y)));
            h = fmaxf(h, 0.0f);
            a0[k] = __builtin_fmaf(h, wa.y, a0[k]);
            a1[k] = __builtin_fmaf(h, wv.y, a1[k]);
            a2[k] = __builtin_fmaf(h, wc.y, a2[k]);

            h = __builtin_fmaf(px[k], wx.z, __builtin_fmaf(py[k], wy.z,
                __builtin_fmaf(pz[k], wz.z, wb.z)));
            h = fmaxf(h, 0.0f);
            a0[k] = __builtin_fmaf(h, wa.z, a0[k]);
            a1[k] = __builtin_fmaf(h, wv.z, a1[k]);
            a2[k] = __builtin_fmaf(h, wc.z, a2[k]);

            h = __builtin_fmaf(px[k], wx.w, __builtin_fmaf(py[k], wy.w,
                __builtin_fmaf(pz[k], wz.w, wb.w)));
            h = fmaxf(h, 0.0f);
            a0[k] = __builtin_fmaf(h, wa.w, a0[k]);
            a1[k] = __builtin_fmaf(h, wv.w, a1[k]);
            a2[k] = __builtin_fmaf(h, wc.w, a2[k]);
        }
    }

    // ---- sigmoid + masked store ----
    #pragma unroll
    for (int k = 0; k < RPT; ++k) {
        const int r = r0 + k * STRIDE;
        const float s0 = 1.0f / (1.0f + __expf(-a0[k]));
        const float s1 = 1.0f / (1.0f + __expf(-a1[k]));
        const float s2 = 1.0f / (1.0f + __expf(-a2[k]));
        out[3*r+0] = hit[k] ? s0 : 0.0f;
        out[3*r+1] = hit[k] ? s1 : 0.0f;
        out[3*r+2] = hit[k] ? s2 : 0.0f;
    }
}

extern "C" void kernel_launch(void* const* d_in, const int* in_sizes, int n_in,
                              void* d_out, int out_size, void* d_ws, size_t ws_size,
                              hipStream_t stream) {
    const float* org    = (const float*)d_in[0];
    const float* dir    = (const float*)d_in[1];
    const float* center = (const float*)d_in[2];
    const float* radius = (const float*)d_in[3];
    const float* w1     = (const float*)d_in[4];
    const float* b1     = (const float*)d_in[5];
    const float* w2     = (const float*)d_in[6];
    const float* b2     = (const float*)d_in[7];
    float* out = (float*)d_out;

    const int grid = N_RAYS / (BLOCK * RPT);   // 256
    st_fused4<<<grid, BLOCK, 0, stream>>>(org, dir, center, radius,
                                          w1, b1, w2, b2, out);
}